// Round 13
// baseline (95.189 us; speedup 1.0000x reference)
//
#include <hip/hip_runtime.h>
#include <stdint.h>

#pragma clang fp contract(off)

typedef __attribute__((ext_vector_type(4))) int i32x4;
typedef __attribute__((ext_vector_type(16))) int i32x16;

#define B_    16
#define C_    128
#define HW_   56
#define L_    3136
#define CO_   128
#define F_    1152
#define M_    50176
#define NT1_  784          // A1 streaming blocks
#define NTC_  448          // GEMM tiles (8 XCD * 56), 112 rows each

// ---- workspace layout (bytes) ----
#define OFF_PRMIN 0        // int[448]
#define OFF_PRMAX 2048     // int[448]
#define OFF_PBMIN 4096     // float[784]
#define OFF_PBMAX 8192     // float[784]
#define OFF_SW    12288    // float scale_w[128]
#define OFF_ZPW   12800    // int zp_w[128]
#define OFF_SXZX  13312    // float {sx, zx}
#define OFF_CNT   13440    // unsigned sync counters: 8 shards x 64B = 512
#define OFF_QS    14080    // int qsum[128]
#define OFF_QW    16384    // int8 qw2[j][ch][o][16] = 147456
#define OFF_RES   163840   // int res[50176][128] (FALLBACK PATH ONLY)

#define HALO_B 29696       // 232 pix x 128 B
#define BS_B   16384
#define POOL_B (HALO_B + 2 * BS_B)   // 62464

__device__ __forceinline__ int read_abit(const int* p) {
    int i = *p;
    if (i > 0 && i < 32) return i;
    float f = __int_as_float(i);
    int fi = (int)f;
    return (fi > 0 && fi < 32) ? fi : 8;
}

__device__ __forceinline__ int swz_tile(int blk) {
    return (blk & 7) * 56 + (blk >> 3);    // bijective on [0,448)
}

// ---- sharded grid barrier (relies on co-residency; counters pre-zeroed) ----
__device__ __forceinline__ void gsync(char* ws) {
    unsigned* base = (unsigned*)(ws + OFF_CNT);
    __syncthreads();
    if (threadIdx.x == 0) {
        __threadfence();                    // release
        atomicAdd(&base[(blockIdx.x & 7) * 16], 1u);
    }
    if (threadIdx.x < 8) {
        while (__hip_atomic_load(&base[threadIdx.x * 16],
                                 __ATOMIC_RELAXED, __HIP_MEMORY_SCOPE_AGENT) < 56u)
            __builtin_amdgcn_s_sleep(2);
    }
    __threadfence();                        // acquire
    __syncthreads();
}

// ---- block-wide reductions (256 threads) ----
__device__ __forceinline__ void block_fminmax(float& mn, float& mx, float* sred) {
    for (int m = 32; m; m >>= 1) {
        mn = fminf(mn, __shfl_xor(mn, m));
        mx = fmaxf(mx, __shfl_xor(mx, m));
    }
    int w = threadIdx.x >> 6;
    if ((threadIdx.x & 63) == 0) { sred[w] = mn; sred[4 + w] = mx; }
    __syncthreads();
    mn = fminf(fminf(sred[0], sred[1]), fminf(sred[2], sred[3]));
    mx = fmaxf(fmaxf(sred[4], sred[5]), fmaxf(sred[6], sred[7]));
    __syncthreads();
}
__device__ __forceinline__ void block_iminmax(int& mn, int& mx, int* ired) {
    for (int m = 32; m; m >>= 1) {
        mn = min(mn, __shfl_xor(mn, m));
        mx = max(mx, __shfl_xor(mx, m));
    }
    int w = threadIdx.x >> 6;
    if ((threadIdx.x & 63) == 0) { ired[w] = mn; ired[4 + w] = mx; }
    __syncthreads();
    mn = min(min(ired[0], ired[1]), min(ired[2], ired[3]));
    mx = max(max(ired[4], ired[5]), max(ired[6], ired[7]));
    __syncthreads();
}
__device__ __forceinline__ int block_isum(int v, int* ired) {
    for (int m = 32; m; m >>= 1) v += __shfl_xor(v, m);
    int w = threadIdx.x >> 6;
    if ((threadIdx.x & 63) == 0) ired[w] = v;
    __syncthreads();
    v = ired[0] + ired[1] + ired[2] + ired[3];
    __syncthreads();
    return v;
}

// =================== A1: x min/max partials (pure streaming) ===================
__global__ __launch_bounds__(256) void kA1(const float4* __restrict__ x4,
                                           char* __restrict__ ws) {
    __shared__ float sred[8];
    float mn = 0.0f, mx = 0.0f;    // padding zeros included
    int base = blockIdx.x * blockDim.x + threadIdx.x;
    int stride = NT1_ * 256;
    #pragma unroll
    for (int k = 0; k < 8; ++k) {
        float4 v = x4[base + k * stride];
        mn = fminf(mn, fminf(fminf(v.x, v.y), fminf(v.z, v.w)));
        mx = fmaxf(mx, fmaxf(fmaxf(v.x, v.y), fmaxf(v.z, v.w)));
    }
    block_fminmax(mn, mx, sred);
    if (threadIdx.x == 0) {
        ((float*)(ws + OFF_PBMIN))[blockIdx.x] = mn;
        ((float*)(ws + OFF_PBMAX))[blockIdx.x] = mx;
    }
}

// ========== A2: reduce partials -> sx/zx; weight quant (sx-independent) ==========
__global__ __launch_bounds__(256) void kA2(const float* __restrict__ wgt,
                                           const int* __restrict__ abit_p,
                                           char* __restrict__ ws) {
    __shared__ float sred[8];
    __shared__ int ired[8];
    if (blockIdx.x == CO_) {
        const float* pbmin = (const float*)(ws + OFF_PBMIN);
        const float* pbmax = (const float*)(ws + OFF_PBMAX);
        float mn = 0.0f, mx = 0.0f;
        for (int i = threadIdx.x; i < NT1_; i += 256) {
            mn = fminf(mn, pbmin[i]);
            mx = fmaxf(mx, pbmax[i]);
        }
        block_fminmax(mn, mx, sred);
        if (threadIdx.x == 0) {
            int abit = read_abit(abit_p);
            float nlv = (float)((1 << abit) - 1);
            float sx = nlv / fmaxf(mx - mn, 1e-8f);
            float zx = rintf(sx * mn) + (float)(1 << (abit - 1));
            ((float*)(ws + OFF_SXZX))[0] = sx;
            ((float*)(ws + OFF_SXZX))[1] = zx;
        }
        return;
    }
    int o = blockIdx.x;
    const float* wr = wgt + o * F_;
    float mn = 3.4e38f, mx = -3.4e38f;
    for (int f = threadIdx.x; f < F_; f += 256) {
        float v = wr[f];
        mn = fminf(mn, v); mx = fmaxf(mx, v);
    }
    block_fminmax(mn, mx, sred);
    float sw = 255.0f / fmaxf(mx - mn, 1e-8f);
    float zw = rintf(sw * mn) + 128.0f;
    signed char* qw = (signed char*)(ws + OFF_QW);
    int qsum = 0;
    for (int f = threadIdx.x; f < F_; f += 256) {
        float q = fminf(fmaxf(rintf(sw * wr[f] - zw), -128.0f), 127.0f);
        int qi = (int)q;
        qsum += qi;
        int c = f / 9, j = f - c * 9;
        qw[j * 16384 + (c >> 4) * 2048 + (o << 4) + (c & 15)] = (signed char)qi;
    }
    qsum = block_isum(qsum, ired);
    if (threadIdx.x == 0) {
        ((int*)(ws + OFF_QS))[o]  = qsum;
        ((int*)(ws + OFF_ZPW))[o] = (int)zw;
        ((float*)(ws + OFF_SW))[o] = sw;
    }
}

// ---- fused: quantize halo in-block + 128x128 GEMM; accs kept in registers ----
template <bool WRITE_RES>
__device__ __forceinline__ void dev_main(const float* __restrict__ x,
                                         const float* __restrict__ bias,
                                         char* __restrict__ ws, char* pool,
                                         int* S_s, int* sq, int* ired,
                                         int abit, float sx, float zx,
                                         i32x16& a00, i32x16& a01,
                                         i32x16& a10, i32x16& a11,
                                         int& mgout) {
    signed char* NB  = (signed char*)pool;
    signed char* Bs0 = (signed char*)(pool + HALO_B);
    signed char* Bs1 = Bs0 + BS_B;
    const signed char* qw = (const signed char*)(ws + OFF_QW);
    const int* zpw = (const int*)(ws + OFF_ZPW);

    int t = threadIdx.x;
    int mg = swz_tile(blockIdx.x) * 112;
    mgout = mg;
    int b = mg / L_, l0 = mg - b * L_;
    int prow0 = l0 / HW_;              // tile = pixel rows prow0, prow0+1
    int nx = 1 << (abit - 1);
    int q0 = min(max(-(int)zx, -nx), nx - 1);
    int pw = (q0 & 255) * 0x01010101;
    int4 pad4; pad4.x = pw; pad4.y = pw; pad4.z = pw; pad4.w = pw;
    const float* xb = x + (size_t)b * C_ * L_;

    // B tap0 prefetch
    int4 br0, br1, br2, br3;
    {
        const int4* src = (const int4*)qw;
        br0 = src[t]; br1 = src[256 + t]; br2 = src[512 + t]; br3 = src[768 + t];
    }

    // H1: q0-fill whole halo (1856 int4 slots)
    #pragma unroll
    for (int i = 0; i < 8; ++i) {
        int s = t + i * 256;
        if (s < 1856) ((int4*)NB)[s] = pad4;
    }
    __syncthreads();

    // H2: quantize interior straight from x into swizzled halo bytes
    {
        float lo = -(float)nx, hif = (float)(nx - 1);
        #pragma unroll
        for (int i = 0; i < 28; ++i) {
            int u = t + i * 256;                   // 7168 float4-units
            int c = u / 56, rem = u - c * 56;
            int ri = rem / 14, f4 = rem - ri * 14;
            int ih = prow0 - 1 + ri;
            if ((unsigned)ih < HW_) {
                float4 v = *(const float4*)(xb + (size_t)c * L_ + ih * HW_ + f4 * 4);
                int ch = c >> 4, byte = c & 15;
                #pragma unroll
                for (int k = 0; k < 4; ++k) {
                    float xv = ((const float*)&v)[k];
                    int qi = (int)fminf(fmaxf(rintf(sx * xv - zx), lo), hif);
                    int pix = ri * 58 + f4 * 4 + k + 1;
                    NB[(pix << 7) + ((ch ^ (pix & 7)) << 4) + byte] = (signed char)qi;
                }
            }
        }
    }
    // write Bs0 from regs; issue tap1 loads
    {
        int4* d = (int4*)Bs0;
        d[t] = br0; d[256 + t] = br1; d[512 + t] = br2; d[768 + t] = br3;
        const int4* src = (const int4*)(qw + BS_B);
        br0 = src[t]; br1 = src[256 + t]; br2 = src[512 + t]; br3 = src[768 + t];
    }
    __syncthreads();

    // per-halo-pixel channel sums from LDS
    if (t < 232) {
        int s = 0;
        #pragma unroll
        for (int ch = 0; ch < 8; ++ch) {
            int4 v = *(const int4*)&NB[(t << 7) + ((ch ^ (t & 7)) << 4)];
            #pragma unroll
            for (int k2 = 0; k2 < 4; ++k2) {
                int wv = ((const int*)&v)[k2];
                s += (int)(signed char)wv + (int)(signed char)(wv >> 8)
                   + (int)(signed char)(wv >> 16) + (int)(signed char)(wv >> 24);
            }
        }
        S_s[t] = s;
    }
    __syncthreads();
    if (t < 128) {                      // per-row 3x3 box sums (dead rows clamped)
        int rl = min(t, 111);
        int l = l0 + rl;
        int oh = l / HW_, ow = l - oh * HW_;
        int ri = oh - prow0 + 1, ci = ow + 1;
        int s = 0;
        #pragma unroll
        for (int dr = -1; dr <= 1; ++dr)
            #pragma unroll
            for (int dc = -1; dc <= 1; ++dc)
                s += S_s[(ri + dr) * 58 + ci + dc];
        sq[t] = s;
    }
    // sq writes ordered before epilogue reads by the K-loop barriers

    int lane = t & 63, w = t >> 6;
    int wm = (w >> 1) << 6;            // 0 / 64
    int wn = (w & 1) << 6;             // 0 / 64
    int r = lane & 31, hi = lane >> 5;

    int pb0, pb1;
    {
        int l = l0 + wm + r;                       // < 96: always real
        int oh = l / HW_, ow = l - oh * HW_;
        pb0 = (oh - prow0 + 1) * 58 + ow + 1;
    }
    {
        int rl = min(wm + 32 + r, 111);            // rows >=112 clamp (masked later)
        int l = l0 + rl;
        int oh = l / HW_, ow = l - oh * HW_;
        pb1 = (oh - prow0 + 1) * 58 + ow + 1;
    }

    #pragma unroll
    for (int i = 0; i < 16; ++i) { a00[i] = 0; a01[i] = 0; a10[i] = 0; a11[i] = 0; }

    // ---- K-loop: 9 taps, double-buffered Bs, ONE barrier/tap, static halo A ----
    #pragma unroll
    for (int j = 0; j < 9; ++j) {
        if (j < 8) {
            int4* d = (int4*)(((j + 1) & 1) ? Bs1 : Bs0);
            d[t] = br0; d[256 + t] = br1; d[512 + t] = br2; d[768 + t] = br3;
            if (j < 7) {
                const int4* src = (const int4*)(qw + (j + 2) * BS_B);
                br0 = src[t]; br1 = src[256 + t]; br2 = src[512 + t]; br3 = src[768 + t];
            }
        }
        const signed char* Bc = (j & 1) ? Bs1 : Bs0;
        int dj = (j / 3 - 1) * 58 + (j % 3 - 1);
        i32x4 af0[4], af1[4], bf0[4], bf1[4];
        #pragma unroll
        for (int kk = 0; kk < 4; ++kk) {
            int ch2 = kk * 2 + hi;
            int p0 = pb0 + dj, p1 = pb1 + dj;
            af0[kk] = *(const i32x4*)&NB[(p0 << 7) + ((ch2 ^ (p0 & 7)) << 4)];
            af1[kk] = *(const i32x4*)&NB[(p1 << 7) + ((ch2 ^ (p1 & 7)) << 4)];
            bf0[kk] = *(const i32x4*)&Bc[ch2 * 2048 + ((wn + r) << 4)];
            bf1[kk] = *(const i32x4*)&Bc[ch2 * 2048 + ((wn + 32 + r) << 4)];
        }
        #pragma unroll
        for (int kk = 0; kk < 4; ++kk) {
            a00 = __builtin_amdgcn_mfma_i32_32x32x32_i8(af0[kk], bf0[kk], a00, 0, 0, 0);
            a01 = __builtin_amdgcn_mfma_i32_32x32x32_i8(af0[kk], bf1[kk], a01, 0, 0, 0);
            a10 = __builtin_amdgcn_mfma_i32_32x32x32_i8(af1[kk], bf0[kk], a10, 0, 0, 0);
            a11 = __builtin_amdgcn_mfma_i32_32x32x32_i8(af1[kk], bf1[kk], a11, 0, 0, 0);
        }
        __syncthreads();
    }

    // ---- epilogue: corrections in-register + block min/max partials ----
    int o0 = wn + r, o1 = wn + 32 + r;
    const int* qs = (const int*)(ws + OFF_QS);
    const float* swp = (const float*)(ws + OFF_SW);
    int zxi = (int)zx;
    int zw0 = zpw[o0], zw1 = zpw[o1];
    int c0 = zxi * qs[o0] + F_ * zw0 * zxi + (int)rintf(swp[o0] * sx * bias[o0]);
    int c1 = zxi * qs[o1] + F_ * zw1 * zxi + (int)rintf(swp[o1] * sx * bias[o1]);
    int lmin = INT32_MAX, lmax = INT32_MIN;
    int* resp = (int*)(ws + OFF_RES);
    #pragma unroll
    for (int g = 0; g < 16; ++g) {
        int sub = (g & 3) + ((g >> 2) << 3) + (hi << 2);
        int r0 = wm + sub, r1 = wm + 32 + sub;     // r0 always < 112
        int s0 = sq[r0], s1 = sq[r1];
        int v00 = a00[g] + zw0 * s0 + c0;
        int v01 = a01[g] + zw1 * s0 + c1;
        int v10 = a10[g] + zw0 * s1 + c0;
        int v11 = a11[g] + zw1 * s1 + c1;
        a00[g] = v00; a01[g] = v01; a10[g] = v10; a11[g] = v11;
        lmin = min(lmin, min(v00, v01));
        lmax = max(lmax, max(v00, v01));
        if (r1 < 112) {
            lmin = min(lmin, min(v10, v11));
            lmax = max(lmax, max(v10, v11));
        }
        if (WRITE_RES) {
            resp[(mg + r0) * CO_ + o0] = v00;
            resp[(mg + r0) * CO_ + o1] = v01;
            if (r1 < 112) {
                resp[(mg + r1) * CO_ + o0] = v10;
                resp[(mg + r1) * CO_ + o1] = v11;
            }
        }
    }
    block_iminmax(lmin, lmax, ired);
    if (t == 0) {
        ((int*)(ws + OFF_PRMIN))[blockIdx.x] = lmin;
        ((int*)(ws + OFF_PRMAX))[blockIdx.x] = lmax;
    }
    __syncthreads();
}

__device__ __forceinline__ void dev_reduce_pr(const char* ws, int* ired,
                                              int& rmin, int& rmax) {
    const int* prmin = (const int*)(ws + OFF_PRMIN);
    const int* prmax = (const int*)(ws + OFF_PRMAX);
    int mn = INT32_MAX, mx = INT32_MIN;
    for (int i = threadIdx.x; i < NTC_; i += 256) {
        mn = min(mn, prmin[i]);
        mx = max(mx, prmax[i]);
    }
    block_iminmax(mn, mx, ired);
    rmin = mn; rmax = mx;
}

// =================== C: fused coop kernel (one gsync) ===================
__global__ __launch_bounds__(256, 2) void kC(const float* __restrict__ x,
                                             const float* __restrict__ bias,
                                             const int* __restrict__ abit_p,
                                             char* __restrict__ ws,
                                             float* __restrict__ out) {
    __shared__ __align__(16) char pool[POOL_B];
    __shared__ int S_s[232];
    __shared__ int sq[128];
    __shared__ int ired[8];

    float sx = ((const float*)(ws + OFF_SXZX))[0];
    float zx = ((const float*)(ws + OFF_SXZX))[1];
    int abit = read_abit(abit_p);

    i32x16 a00, a01, a10, a11;
    int mg;
    dev_main<false>(x, bias, ws, pool, S_s, sq, ired, abit, sx, zx,
                    a00, a01, a10, a11, mg);
    gsync(ws);

    int rmin, rmax;
    dev_reduce_pr(ws, ired, rmin, rmax);

    // ---- P4: requant + dequant from registers; two 64-row transpose rounds ----
    const float* swp = (const float*)(ws + OFF_SW);
    int t = threadIdx.x;
    int b = mg / L_, l0 = mg - b * L_;
    int lane = t & 63, w = t >> 6;
    int wm = (w >> 1) << 6, wn = (w & 1) << 6;
    int r = lane & 31, hi = lane >> 5;
    int o0 = wn + r, o1 = wn + 32 + r;
    int nx = 1 << (abit - 1);
    float nlev = (float)((1 << abit) - 1);
    float sr = nlev / fmaxf((float)rmax - (float)rmin, 1e-8f);
    float zr = rintf(sr * (float)rmin) + (float)nx;
    float lo = -(float)nx, hiq = (float)(nx - 1);
    float swsx0 = swp[o0] * sx, swsx1 = swp[o1] * sx;
    float* tile = (float*)pool;        // [64][129] f32 = 33024 B

    #pragma unroll
    for (int rid = 0; rid < 2; ++rid) {
        __syncthreads();
        if (wm == rid * 64) {
            #pragma unroll
            for (int g = 0; g < 16; ++g) {
                int sub = (g & 3) + ((g >> 2) << 3) + (hi << 2);
                float qa = fminf(fmaxf(rintf(sr * (float)a00[g] - zr), lo), hiq);
                float qb = fminf(fmaxf(rintf(sr * (float)a01[g] - zr), lo), hiq);
                float qc = fminf(fmaxf(rintf(sr * (float)a10[g] - zr), lo), hiq);
                float qd = fminf(fmaxf(rintf(sr * (float)a11[g] - zr), lo), hiq);
                tile[sub * 129 + o0] = ((qa + zr) / sr) / swsx0;
                tile[sub * 129 + o1] = ((qb + zr) / sr) / swsx1;
                tile[(32 + sub) * 129 + o0] = ((qc + zr) / sr) / swsx0;
                tile[(32 + sub) * 129 + o1] = ((qd + zr) / sr) / swsx1;
            }
        }
        __syncthreads();
        int nrows = (rid == 0) ? 64 : 48;          // rows 112..127 are dead
        #pragma unroll
        for (int i = 0; i < 8; ++i) {
            int o = (t >> 4) + i * 16;
            int l4 = (t & 15) * 4;
            if (l4 < nrows) {
                float4 f;
                #pragma unroll
                for (int jj = 0; jj < 4; ++jj)
                    ((float*)&f)[jj] = tile[(l4 + jj) * 129 + o];
                *(float4*)(out + ((size_t)(b * CO_ + o)) * L_ + l0 + rid * 64 + l4) = f;
            }
        }
    }
}

// =================== fallback (non-cooperative) path ===================
__global__ __launch_bounds__(256, 2) void fbC(const float* __restrict__ x,
                                              const float* __restrict__ bias,
                                              const int* __restrict__ abit_p,
                                              char* __restrict__ ws) {
    __shared__ __align__(16) char pool[POOL_B];
    __shared__ int S_s[232];
    __shared__ int sq[128];
    __shared__ int ired[8];
    float sx = ((const float*)(ws + OFF_SXZX))[0];
    float zx = ((const float*)(ws + OFF_SXZX))[1];
    int abit = read_abit(abit_p);
    i32x16 a00, a01, a10, a11;
    int mg;
    dev_main<true>(x, bias, ws, pool, S_s, sq, ired, abit, sx, zx,
                   a00, a01, a10, a11, mg);
}

__global__ __launch_bounds__(256) void fbD(const int* __restrict__ abit_p,
                                           char* __restrict__ ws,
                                           float* __restrict__ out) {
    __shared__ int tile[64 * 65];
    __shared__ int ired[8];
    float sxv = ((const float*)(ws + OFF_SXZX))[0];
    int abit = read_abit(abit_p);
    float nlv = (float)((1 << abit) - 1);
    int rmin, rmax;
    dev_reduce_pr(ws, ired, rmin, rmax);

    const int* res = (const int*)(ws + OFF_RES);
    const float* scale_w = (const float*)(ws + OFF_SW);
    int t = threadIdx.x;
    int bid = blockIdx.x;
    int lcq = bid % 49; int tmp2 = bid / 49; int ocq = tmp2 & 1; int b = tmp2 >> 1;
    int l0 = lcq * 64, o0 = ocq * 64;

    const int* resb = res + ((size_t)(b * L_ + l0)) * CO_ + o0;
    #pragma unroll
    for (int i = 0; i < 4; ++i) {
        int lr = (t >> 4) + i * 16;
        int oc4 = (t & 15) * 4;
        int4 v = *(const int4*)(resb + lr * CO_ + oc4);
        int* d = &tile[lr * 65 + oc4];
        d[0] = v.x; d[1] = v.y; d[2] = v.z; d[3] = v.w;
    }
    int nxq = 1 << (abit - 1);
    float sr = nlv / fmaxf((float)rmax - (float)rmin, 1e-8f);
    float zr = rintf(sr * (float)rmin) + (float)nxq;
    float lo = -(float)nxq, hiq = (float)(nxq - 1);
    __syncthreads();
    #pragma unroll
    for (int i = 0; i < 4; ++i) {
        int o = (t >> 4) + i * 16;
        int l4 = (t & 15) * 4;
        float swsx = scale_w[o0 + o] * sxv;
        float4 f;
        #pragma unroll
        for (int jj = 0; jj < 4; ++jj) {
            int rv = tile[(l4 + jj) * 65 + o];
            float q = fminf(fmaxf(rintf(sr * (float)rv - zr), lo), hiq);
            ((float*)&f)[jj] = ((q + zr) / sr) / swsx;
        }
        *(float4*)(out + ((size_t)(b * CO_ + o0 + o)) * L_ + l0 + l4) = f;
    }
}

// ---------------- launch ----------------

extern "C" void kernel_launch(void* const* d_in, const int* in_sizes, int n_in,
                              void* d_out, int out_size, void* d_ws, size_t ws_size,
                              hipStream_t stream) {
    const float* x      = (const float*)d_in[0];
    const float* weight = (const float*)d_in[1];
    const float* bias   = (const float*)d_in[2];
    const int*   abit   = (const int*)d_in[3];
    float* out = (float*)d_out;
    char* ws = (char*)d_ws;

    int dev = 0;
    hipGetDevice(&dev);
    int ncu = 0;
    hipDeviceGetAttribute(&ncu, hipDeviceAttributeMultiprocessorCount, dev);
    int nb = 0;
    hipOccupancyMaxActiveBlocksPerMultiprocessor(&nb, (const void*)kC, 256, 0);

    kA1<<<NT1_, 256, 0, stream>>>((const float4*)x, ws);
    kA2<<<CO_ + 1, 256, 0, stream>>>(weight, abit, ws);

    if (nb > 0 && (long)nb * (long)ncu >= NTC_) {
        hipMemsetAsync(ws + OFF_CNT, 0, 512, stream);
        kC<<<NTC_, 256, 0, stream>>>(x, bias, abit, ws, out);
    } else {
        fbC<<<NTC_, 256, 0, stream>>>(x, bias, abit, ws);
        fbD<<<1568, 256, 0, stream>>>(abit, ws, out);
    }
}

// Round 14
// 91.583 us; speedup vs baseline: 1.0394x; 1.0394x over previous
//
#include <hip/hip_runtime.h>
#include <stdint.h>

#pragma clang fp contract(off)

typedef __attribute__((ext_vector_type(4))) int i32x4;
typedef __attribute__((ext_vector_type(16))) int i32x16;

#define B_    16
#define C_    128
#define HW_   56
#define L_    3136
#define CO_   128
#define F_    1152
#define M_    50176
#define NT1_  784          // A1 streaming blocks
#define NTC_  448          // GEMM tiles (8 XCD * 56), 112 rows each

// ---- workspace layout (bytes) ----
#define OFF_PRMIN 0        // int[448]
#define OFF_PRMAX 2048     // int[448]
#define OFF_PBMIN 4096     // float[784]
#define OFF_PBMAX 8192     // float[784]
#define OFF_SW    12288    // float scale_w[128]
#define OFF_ZPW   12800    // int zp_w[128]
#define OFF_SXZX  13312    // float {sx, zx}
#define OFF_CNT   13440    // unsigned sync counters: 8 shards x 64B = 512
#define OFF_QS    14080    // int qsum[128]
#define OFF_QW    16384    // int8 qw2[j][ch][o][16] = 147456
#define OFF_RES   163840   // int res[50176][128] (FALLBACK PATH ONLY)

#define HALO_B 29696       // 232 pix x 128 B
#define BS_B   16384
#define POOL_B (HALO_B + 2 * BS_B)   // 62464

__device__ __forceinline__ int read_abit(const int* p) {
    int i = *p;
    if (i > 0 && i < 32) return i;
    float f = __int_as_float(i);
    int fi = (int)f;
    return (fi > 0 && fi < 32) ? fi : 8;
}

__device__ __forceinline__ int swz_tile(int blk) {
    return (blk & 7) * 56 + (blk >> 3);    // bijective on [0,448)
}

// ---- sharded grid barrier (relies on co-residency; counters pre-zeroed) ----
__device__ __forceinline__ void gsync(char* ws) {
    unsigned* base = (unsigned*)(ws + OFF_CNT);
    __syncthreads();
    if (threadIdx.x == 0) {
        __threadfence();                    // release
        atomicAdd(&base[(blockIdx.x & 7) * 16], 1u);
    }
    if (threadIdx.x < 8) {
        while (__hip_atomic_load(&base[threadIdx.x * 16],
                                 __ATOMIC_RELAXED, __HIP_MEMORY_SCOPE_AGENT) < 56u)
            __builtin_amdgcn_s_sleep(2);
    }
    __threadfence();                        // acquire
    __syncthreads();
}

// ---- block-wide reductions (256 threads) ----
__device__ __forceinline__ void block_fminmax(float& mn, float& mx, float* sred) {
    for (int m = 32; m; m >>= 1) {
        mn = fminf(mn, __shfl_xor(mn, m));
        mx = fmaxf(mx, __shfl_xor(mx, m));
    }
    int w = threadIdx.x >> 6;
    if ((threadIdx.x & 63) == 0) { sred[w] = mn; sred[4 + w] = mx; }
    __syncthreads();
    mn = fminf(fminf(sred[0], sred[1]), fminf(sred[2], sred[3]));
    mx = fmaxf(fmaxf(sred[4], sred[5]), fmaxf(sred[6], sred[7]));
    __syncthreads();
}
__device__ __forceinline__ void block_iminmax(int& mn, int& mx, int* ired) {
    for (int m = 32; m; m >>= 1) {
        mn = min(mn, __shfl_xor(mn, m));
        mx = max(mx, __shfl_xor(mx, m));
    }
    int w = threadIdx.x >> 6;
    if ((threadIdx.x & 63) == 0) { ired[w] = mn; ired[4 + w] = mx; }
    __syncthreads();
    mn = min(min(ired[0], ired[1]), min(ired[2], ired[3]));
    mx = max(max(ired[4], ired[5]), max(ired[6], ired[7]));
    __syncthreads();
}
__device__ __forceinline__ int block_isum(int v, int* ired) {
    for (int m = 32; m; m >>= 1) v += __shfl_xor(v, m);
    int w = threadIdx.x >> 6;
    if ((threadIdx.x & 63) == 0) ired[w] = v;
    __syncthreads();
    v = ired[0] + ired[1] + ired[2] + ired[3];
    __syncthreads();
    return v;
}

// =================== A1: x min/max partials (pure streaming) ===================
__global__ __launch_bounds__(256) void kA1(const float4* __restrict__ x4,
                                           char* __restrict__ ws) {
    __shared__ float sred[8];
    float mn = 0.0f, mx = 0.0f;    // padding zeros included
    int base = blockIdx.x * blockDim.x + threadIdx.x;
    int stride = NT1_ * 256;
    #pragma unroll
    for (int k = 0; k < 8; ++k) {
        float4 v = x4[base + k * stride];
        mn = fminf(mn, fminf(fminf(v.x, v.y), fminf(v.z, v.w)));
        mx = fmaxf(mx, fmaxf(fmaxf(v.x, v.y), fmaxf(v.z, v.w)));
    }
    block_fminmax(mn, mx, sred);
    if (threadIdx.x == 0) {
        ((float*)(ws + OFF_PBMIN))[blockIdx.x] = mn;
        ((float*)(ws + OFF_PBMAX))[blockIdx.x] = mx;
    }
}

// ========== A2: reduce partials -> sx/zx; weight quant (sx-independent) ==========
__global__ __launch_bounds__(256) void kA2(const float* __restrict__ wgt,
                                           const int* __restrict__ abit_p,
                                           char* __restrict__ ws) {
    __shared__ float sred[8];
    __shared__ int ired[8];
    if (blockIdx.x == CO_) {
        const float* pbmin = (const float*)(ws + OFF_PBMIN);
        const float* pbmax = (const float*)(ws + OFF_PBMAX);
        float mn = 0.0f, mx = 0.0f;
        for (int i = threadIdx.x; i < NT1_; i += 256) {
            mn = fminf(mn, pbmin[i]);
            mx = fmaxf(mx, pbmax[i]);
        }
        block_fminmax(mn, mx, sred);
        if (threadIdx.x == 0) {
            int abit = read_abit(abit_p);
            float nlv = (float)((1 << abit) - 1);
            float sx = nlv / fmaxf(mx - mn, 1e-8f);
            float zx = rintf(sx * mn) + (float)(1 << (abit - 1));
            ((float*)(ws + OFF_SXZX))[0] = sx;
            ((float*)(ws + OFF_SXZX))[1] = zx;
        }
        return;
    }
    int o = blockIdx.x;
    const float* wr = wgt + o * F_;
    float mn = 3.4e38f, mx = -3.4e38f;
    for (int f = threadIdx.x; f < F_; f += 256) {
        float v = wr[f];
        mn = fminf(mn, v); mx = fmaxf(mx, v);
    }
    block_fminmax(mn, mx, sred);
    float sw = 255.0f / fmaxf(mx - mn, 1e-8f);
    float zw = rintf(sw * mn) + 128.0f;
    signed char* qw = (signed char*)(ws + OFF_QW);
    int qsum = 0;
    for (int f = threadIdx.x; f < F_; f += 256) {
        float q = fminf(fmaxf(rintf(sw * wr[f] - zw), -128.0f), 127.0f);
        int qi = (int)q;
        qsum += qi;
        int c = f / 9, j = f - c * 9;
        qw[j * 16384 + (c >> 4) * 2048 + (o << 4) + (c & 15)] = (signed char)qi;
    }
    qsum = block_isum(qsum, ired);
    if (threadIdx.x == 0) {
        ((int*)(ws + OFF_QS))[o]  = qsum;
        ((int*)(ws + OFF_ZPW))[o] = (int)zw;
        ((float*)(ws + OFF_SW))[o] = sw;
    }
}

// ---- fused: quantize halo in-block + 128x128 GEMM; accs kept in registers ----
// Quantizer: wave w owns halo row w; lanes 0..55 read x[c][row][lane] coalesced,
// pack 16 channels -> int4, 8x ds_write_b128 into swizzled halo. S sums inline.
template <bool WRITE_RES>
__device__ __forceinline__ void dev_main(const float* __restrict__ x,
                                         const float* __restrict__ bias,
                                         char* __restrict__ ws, char* pool,
                                         int* S_s, int* sq, int* ired,
                                         int abit, float sx, float zx,
                                         i32x16& a00, i32x16& a01,
                                         i32x16& a10, i32x16& a11,
                                         int& mgout) {
    signed char* NB  = (signed char*)pool;
    signed char* Bs0 = (signed char*)(pool + HALO_B);
    signed char* Bs1 = Bs0 + BS_B;
    const signed char* qw = (const signed char*)(ws + OFF_QW);
    const int* zpw = (const int*)(ws + OFF_ZPW);

    int t = threadIdx.x;
    int mg = swz_tile(blockIdx.x) * 112;
    mgout = mg;
    int b = mg / L_, l0 = mg - b * L_;
    int prow0 = l0 / HW_;              // tile = pixel rows prow0, prow0+1
    int nx = 1 << (abit - 1);
    int q0 = min(max(-(int)zx, -nx), nx - 1);
    int pw = (q0 & 255) * 0x01010101;
    int4 pad4; pad4.x = pw; pad4.y = pw; pad4.z = pw; pad4.w = pw;
    int padS = C_ * q0;
    const float* xb = x + (size_t)b * C_ * L_;

    // B tap0 prefetch
    int4 br0, br1, br2, br3;
    {
        const int4* src = (const int4*)qw;
        br0 = src[t]; br1 = src[256 + t]; br2 = src[512 + t]; br3 = src[768 + t];
    }

    // H1: q0-fill whole halo (1856 int4 slots) + S_s = padS
    #pragma unroll
    for (int i = 0; i < 8; ++i) {
        int s = t + i * 256;
        if (s < 1856) ((int4*)NB)[s] = pad4;
    }
    if (t < 232) S_s[t] = padS;
    __syncthreads();

    // H2: per-wave row quantize (transpose-pack, int4 LDS writes)
    {
        int wv_ = t >> 6, lane_ = t & 63;
        int ih = prow0 - 1 + wv_;
        if (lane_ < 56 && (unsigned)ih < HW_) {
            const float* xrow = xb + ih * HW_ + lane_;
            float lo = -(float)nx, hif = (float)(nx - 1);
            int pix = wv_ * 58 + 1 + lane_;
            int psum = 0;
            #pragma unroll
            for (int cg = 0; cg < 8; ++cg) {
                int wds[4];
                #pragma unroll
                for (int k = 0; k < 4; ++k) {
                    int wvv = 0;
                    #pragma unroll
                    for (int e = 0; e < 4; ++e) {
                        int c = cg * 16 + k * 4 + e;
                        float xv = xrow[(size_t)c * L_];
                        int qi = (int)fminf(fmaxf(rintf(sx * xv - zx), lo), hif);
                        psum += qi;
                        wvv |= (qi & 255) << (8 * e);
                    }
                    wds[k] = wvv;
                }
                int4 vv; vv.x = wds[0]; vv.y = wds[1]; vv.z = wds[2]; vv.w = wds[3];
                *(int4*)&NB[(pix << 7) + ((cg ^ (pix & 7)) << 4)] = vv;
            }
            S_s[pix] = psum;
        }
    }
    // write Bs0 from regs; issue tap1 loads
    {
        int4* d = (int4*)Bs0;
        d[t] = br0; d[256 + t] = br1; d[512 + t] = br2; d[768 + t] = br3;
        const int4* src = (const int4*)(qw + BS_B);
        br0 = src[t]; br1 = src[256 + t]; br2 = src[512 + t]; br3 = src[768 + t];
    }
    __syncthreads();

    if (t < 128) {                      // per-row 3x3 box sums (dead rows clamped)
        int rl = min(t, 111);
        int l = l0 + rl;
        int oh = l / HW_, ow = l - oh * HW_;
        int ri = oh - prow0 + 1, ci = ow + 1;
        int s = 0;
        #pragma unroll
        for (int dr = -1; dr <= 1; ++dr)
            #pragma unroll
            for (int dc = -1; dc <= 1; ++dc)
                s += S_s[(ri + dr) * 58 + ci + dc];
        sq[t] = s;
    }
    // sq writes ordered before epilogue reads by the K-loop barriers

    int lane = t & 63, w = t >> 6;
    int wm = (w >> 1) << 6;            // 0 / 64
    int wn = (w & 1) << 6;             // 0 / 64
    int r = lane & 31, hi = lane >> 5;

    int pb0, pb1;
    {
        int l = l0 + wm + r;                       // < 96: always real
        int oh = l / HW_, ow = l - oh * HW_;
        pb0 = (oh - prow0 + 1) * 58 + ow + 1;
    }
    {
        int rl = min(wm + 32 + r, 111);            // rows >=112 clamp (masked later)
        int l = l0 + rl;
        int oh = l / HW_, ow = l - oh * HW_;
        pb1 = (oh - prow0 + 1) * 58 + ow + 1;
    }

    #pragma unroll
    for (int i = 0; i < 16; ++i) { a00[i] = 0; a01[i] = 0; a10[i] = 0; a11[i] = 0; }

    // ---- K-loop: 9 taps, double-buffered Bs, ONE barrier/tap, static halo A ----
    #pragma unroll
    for (int j = 0; j < 9; ++j) {
        if (j < 8) {
            int4* d = (int4*)(((j + 1) & 1) ? Bs1 : Bs0);
            d[t] = br0; d[256 + t] = br1; d[512 + t] = br2; d[768 + t] = br3;
            if (j < 7) {
                const int4* src = (const int4*)(qw + (j + 2) * BS_B);
                br0 = src[t]; br1 = src[256 + t]; br2 = src[512 + t]; br3 = src[768 + t];
            }
        }
        const signed char* Bc = (j & 1) ? Bs1 : Bs0;
        int dj = (j / 3 - 1) * 58 + (j % 3 - 1);
        i32x4 af0[4], af1[4], bf0[4], bf1[4];
        #pragma unroll
        for (int kk = 0; kk < 4; ++kk) {
            int ch2 = kk * 2 + hi;
            int p0 = pb0 + dj, p1 = pb1 + dj;
            af0[kk] = *(const i32x4*)&NB[(p0 << 7) + ((ch2 ^ (p0 & 7)) << 4)];
            af1[kk] = *(const i32x4*)&NB[(p1 << 7) + ((ch2 ^ (p1 & 7)) << 4)];
            bf0[kk] = *(const i32x4*)&Bc[ch2 * 2048 + ((wn + r) << 4)];
            bf1[kk] = *(const i32x4*)&Bc[ch2 * 2048 + ((wn + 32 + r) << 4)];
        }
        #pragma unroll
        for (int kk = 0; kk < 4; ++kk) {
            a00 = __builtin_amdgcn_mfma_i32_32x32x32_i8(af0[kk], bf0[kk], a00, 0, 0, 0);
            a01 = __builtin_amdgcn_mfma_i32_32x32x32_i8(af0[kk], bf1[kk], a01, 0, 0, 0);
            a10 = __builtin_amdgcn_mfma_i32_32x32x32_i8(af1[kk], bf0[kk], a10, 0, 0, 0);
            a11 = __builtin_amdgcn_mfma_i32_32x32x32_i8(af1[kk], bf1[kk], a11, 0, 0, 0);
        }
        __syncthreads();
    }

    // ---- epilogue: corrections in-register + block min/max partials ----
    int o0 = wn + r, o1 = wn + 32 + r;
    const int* qs = (const int*)(ws + OFF_QS);
    const float* swp = (const float*)(ws + OFF_SW);
    int zxi = (int)zx;
    int zw0 = zpw[o0], zw1 = zpw[o1];
    int c0 = zxi * qs[o0] + F_ * zw0 * zxi + (int)rintf(swp[o0] * sx * bias[o0]);
    int c1 = zxi * qs[o1] + F_ * zw1 * zxi + (int)rintf(swp[o1] * sx * bias[o1]);
    int lmin = INT32_MAX, lmax = INT32_MIN;
    int* resp = (int*)(ws + OFF_RES);
    #pragma unroll
    for (int g = 0; g < 16; ++g) {
        int sub = (g & 3) + ((g >> 2) << 3) + (hi << 2);
        int r0 = wm + sub, r1 = wm + 32 + sub;     // r0 always < 112
        int s0 = sq[r0], s1 = sq[r1];
        int v00 = a00[g] + zw0 * s0 + c0;
        int v01 = a01[g] + zw1 * s0 + c1;
        int v10 = a10[g] + zw0 * s1 + c0;
        int v11 = a11[g] + zw1 * s1 + c1;
        a00[g] = v00; a01[g] = v01; a10[g] = v10; a11[g] = v11;
        lmin = min(lmin, min(v00, v01));
        lmax = max(lmax, max(v00, v01));
        if (r1 < 112) {
            lmin = min(lmin, min(v10, v11));
            lmax = max(lmax, max(v10, v11));
        }
        if (WRITE_RES) {
            resp[(mg + r0) * CO_ + o0] = v00;
            resp[(mg + r0) * CO_ + o1] = v01;
            if (r1 < 112) {
                resp[(mg + r1) * CO_ + o0] = v10;
                resp[(mg + r1) * CO_ + o1] = v11;
            }
        }
    }
    block_iminmax(lmin, lmax, ired);
    if (t == 0) {
        ((int*)(ws + OFF_PRMIN))[blockIdx.x] = lmin;
        ((int*)(ws + OFF_PRMAX))[blockIdx.x] = lmax;
    }
    __syncthreads();
}

__device__ __forceinline__ void dev_reduce_pr(const char* ws, int* ired,
                                              int& rmin, int& rmax) {
    const int* prmin = (const int*)(ws + OFF_PRMIN);
    const int* prmax = (const int*)(ws + OFF_PRMAX);
    int mn = INT32_MAX, mx = INT32_MIN;
    for (int i = threadIdx.x; i < NTC_; i += 256) {
        mn = min(mn, prmin[i]);
        mx = max(mx, prmax[i]);
    }
    block_iminmax(mn, mx, ired);
    rmin = mn; rmax = mx;
}

// =================== C: fused coop kernel (one gsync) ===================
__global__ __launch_bounds__(256, 2) void kC(const float* __restrict__ x,
                                             const float* __restrict__ bias,
                                             const int* __restrict__ abit_p,
                                             char* __restrict__ ws,
                                             float* __restrict__ out) {
    __shared__ __align__(16) char pool[POOL_B];
    __shared__ int S_s[232];
    __shared__ int sq[128];
    __shared__ int ired[8];

    float sx = ((const float*)(ws + OFF_SXZX))[0];
    float zx = ((const float*)(ws + OFF_SXZX))[1];
    int abit = read_abit(abit_p);

    i32x16 a00, a01, a10, a11;
    int mg;
    dev_main<false>(x, bias, ws, pool, S_s, sq, ired, abit, sx, zx,
                    a00, a01, a10, a11, mg);
    gsync(ws);

    int rmin, rmax;
    dev_reduce_pr(ws, ired, rmin, rmax);

    // ---- P4: requant + dequant from registers; two 64-row transpose rounds ----
    const float* swp = (const float*)(ws + OFF_SW);
    int t = threadIdx.x;
    int b = mg / L_, l0 = mg - b * L_;
    int lane = t & 63, w = t >> 6;
    int wm = (w >> 1) << 6, wn = (w & 1) << 6;
    int r = lane & 31, hi = lane >> 5;
    int o0 = wn + r, o1 = wn + 32 + r;
    int nx = 1 << (abit - 1);
    float nlev = (float)((1 << abit) - 1);
    float sr = nlev / fmaxf((float)rmax - (float)rmin, 1e-8f);
    float zr = rintf(sr * (float)rmin) + (float)nx;
    float lo = -(float)nx, hiq = (float)(nx - 1);
    float swsx0 = swp[o0] * sx, swsx1 = swp[o1] * sx;
    float* tile = (float*)pool;        // [64][129] f32 = 33024 B

    #pragma unroll
    for (int rid = 0; rid < 2; ++rid) {
        __syncthreads();
        if (wm == rid * 64) {
            #pragma unroll
            for (int g = 0; g < 16; ++g) {
                int sub = (g & 3) + ((g >> 2) << 3) + (hi << 2);
                float qa = fminf(fmaxf(rintf(sr * (float)a00[g] - zr), lo), hiq);
                float qb = fminf(fmaxf(rintf(sr * (float)a01[g] - zr), lo), hiq);
                float qc = fminf(fmaxf(rintf(sr * (float)a10[g] - zr), lo), hiq);
                float qd = fminf(fmaxf(rintf(sr * (float)a11[g] - zr), lo), hiq);
                tile[sub * 129 + o0] = ((qa + zr) / sr) / swsx0;
                tile[sub * 129 + o1] = ((qb + zr) / sr) / swsx1;
                tile[(32 + sub) * 129 + o0] = ((qc + zr) / sr) / swsx0;
                tile[(32 + sub) * 129 + o1] = ((qd + zr) / sr) / swsx1;
            }
        }
        __syncthreads();
        int nrows = (rid == 0) ? 64 : 48;          // rows 112..127 are dead
        #pragma unroll
        for (int i = 0; i < 8; ++i) {
            int o = (t >> 4) + i * 16;
            int l4 = (t & 15) * 4;
            if (l4 < nrows) {
                float4 f;
                #pragma unroll
                for (int jj = 0; jj < 4; ++jj)
                    ((float*)&f)[jj] = tile[(l4 + jj) * 129 + o];
                *(float4*)(out + ((size_t)(b * CO_ + o)) * L_ + l0 + rid * 64 + l4) = f;
            }
        }
    }
}

// =================== fallback (non-cooperative) path ===================
__global__ __launch_bounds__(256, 2) void fbC(const float* __restrict__ x,
                                              const float* __restrict__ bias,
                                              const int* __restrict__ abit_p,
                                              char* __restrict__ ws) {
    __shared__ __align__(16) char pool[POOL_B];
    __shared__ int S_s[232];
    __shared__ int sq[128];
    __shared__ int ired[8];
    float sx = ((const float*)(ws + OFF_SXZX))[0];
    float zx = ((const float*)(ws + OFF_SXZX))[1];
    int abit = read_abit(abit_p);
    i32x16 a00, a01, a10, a11;
    int mg;
    dev_main<true>(x, bias, ws, pool, S_s, sq, ired, abit, sx, zx,
                   a00, a01, a10, a11, mg);
}

__global__ __launch_bounds__(256) void fbD(const int* __restrict__ abit_p,
                                           char* __restrict__ ws,
                                           float* __restrict__ out) {
    __shared__ int tile[64 * 65];
    __shared__ int ired[8];
    float sxv = ((const float*)(ws + OFF_SXZX))[0];
    int abit = read_abit(abit_p);
    float nlv = (float)((1 << abit) - 1);
    int rmin, rmax;
    dev_reduce_pr(ws, ired, rmin, rmax);

    const int* res = (const int*)(ws + OFF_RES);
    const float* scale_w = (const float*)(ws + OFF_SW);
    int t = threadIdx.x;
    int bid = blockIdx.x;
    int lcq = bid % 49; int tmp2 = bid / 49; int ocq = tmp2 & 1; int b = tmp2 >> 1;
    int l0 = lcq * 64, o0 = ocq * 64;

    const int* resb = res + ((size_t)(b * L_ + l0)) * CO_ + o0;
    #pragma unroll
    for (int i = 0; i < 4; ++i) {
        int lr = (t >> 4) + i * 16;
        int oc4 = (t & 15) * 4;
        int4 v = *(const int4*)(resb + lr * CO_ + oc4);
        int* d = &tile[lr * 65 + oc4];
        d[0] = v.x; d[1] = v.y; d[2] = v.z; d[3] = v.w;
    }
    int nxq = 1 << (abit - 1);
    float sr = nlv / fmaxf((float)rmax - (float)rmin, 1e-8f);
    float zr = rintf(sr * (float)rmin) + (float)nxq;
    float lo = -(float)nxq, hiq = (float)(nxq - 1);
    __syncthreads();
    #pragma unroll
    for (int i = 0; i < 4; ++i) {
        int o = (t >> 4) + i * 16;
        int l4 = (t & 15) * 4;
        float swsx = scale_w[o0 + o] * sxv;
        float4 f;
        #pragma unroll
        for (int jj = 0; jj < 4; ++jj) {
            int rv = tile[(l4 + jj) * 65 + o];
            float q = fminf(fmaxf(rintf(sr * (float)rv - zr), lo), hiq);
            ((float*)&f)[jj] = ((q + zr) / sr) / swsx;
        }
        *(float4*)(out + ((size_t)(b * CO_ + o0 + o)) * L_ + l0 + l4) = f;
    }
}

// ---------------- launch ----------------

extern "C" void kernel_launch(void* const* d_in, const int* in_sizes, int n_in,
                              void* d_out, int out_size, void* d_ws, size_t ws_size,
                              hipStream_t stream) {
    const float* x      = (const float*)d_in[0];
    const float* weight = (const float*)d_in[1];
    const float* bias   = (const float*)d_in[2];
    const int*   abit   = (const int*)d_in[3];
    float* out = (float*)d_out;
    char* ws = (char*)d_ws;

    int dev = 0;
    hipGetDevice(&dev);
    int ncu = 0;
    hipDeviceGetAttribute(&ncu, hipDeviceAttributeMultiprocessorCount, dev);
    int nb = 0;
    hipOccupancyMaxActiveBlocksPerMultiprocessor(&nb, (const void*)kC, 256, 0);

    kA1<<<NT1_, 256, 0, stream>>>((const float4*)x, ws);
    kA2<<<CO_ + 1, 256, 0, stream>>>(weight, abit, ws);

    if (nb > 0 && (long)nb * (long)ncu >= NTC_) {
        hipMemsetAsync(ws + OFF_CNT, 0, 512, stream);
        kC<<<NTC_, 256, 0, stream>>>(x, bias, abit, ws, out);
    } else {
        fbC<<<NTC_, 256, 0, stream>>>(x, bias, abit, ws);
        fbD<<<1568, 256, 0, stream>>>(abit, ws, out);
    }
}

// Round 15
// 55.033 us; speedup vs baseline: 1.7297x; 1.6641x over previous
//
#include <hip/hip_runtime.h>
#include <stdint.h>

#pragma clang fp contract(off)

typedef __attribute__((ext_vector_type(4))) int i32x4;
typedef __attribute__((ext_vector_type(16))) int i32x16;

#define B_    16
#define C_    128
#define HW_   56
#define L_    3136
#define CO_   128
#define F_    1152
#define M_    50176
#define NT_   784          // GEMM tiles (8 XCD * 98), 64 rows each

// ---- workspace layout (bytes) ----
#define OFF_PBMIN 0        // float[784]
#define OFF_PBMAX 4096     // float[784]
#define OFF_PRMIN 8192     // int[784]
#define OFF_PRMAX 12288    // int[784]
#define OFF_SW    16384    // float scale_w[128]
#define OFF_ZPW   16896    // int zp_w[128]
#define OFF_SXZX  17408    // float {sx, zx}
#define OFF_QS    17536    // int qsum[128]
#define OFF_QW    18432    // int8 qw2[j][ch][o][16] = 147456
#define OFF_QX    165888   // int8 qx_t[b][l][c] = 6422528
#define OFF_S     6588416  // int S[b][3136] = 200704
#define OFF_RES   6789120  // int res[50176][128] = 25690112 (end ~32.5MB)

__device__ __forceinline__ int read_abit(const int* p) {
    int i = *p;
    if (i > 0 && i < 32) return i;
    float f = __int_as_float(i);
    int fi = (int)f;
    return (fi > 0 && fi < 32) ? fi : 8;
}

__device__ __forceinline__ int swz_tile(int blk) {
    return (blk & 7) * 98 + (blk >> 3);    // bijective on [0,784)
}

// ---- block-wide reductions (256 threads) ----
__device__ __forceinline__ void block_fminmax(float& mn, float& mx, float* sred) {
    for (int m = 32; m; m >>= 1) {
        mn = fminf(mn, __shfl_xor(mn, m));
        mx = fmaxf(mx, __shfl_xor(mx, m));
    }
    int w = threadIdx.x >> 6;
    if ((threadIdx.x & 63) == 0) { sred[w] = mn; sred[4 + w] = mx; }
    __syncthreads();
    mn = fminf(fminf(sred[0], sred[1]), fminf(sred[2], sred[3]));
    mx = fmaxf(fmaxf(sred[4], sred[5]), fmaxf(sred[6], sred[7]));
    __syncthreads();
}
__device__ __forceinline__ void block_iminmax(int& mn, int& mx, int* ired) {
    for (int m = 32; m; m >>= 1) {
        mn = min(mn, __shfl_xor(mn, m));
        mx = max(mx, __shfl_xor(mx, m));
    }
    int w = threadIdx.x >> 6;
    if ((threadIdx.x & 63) == 0) { ired[w] = mn; ired[4 + w] = mx; }
    __syncthreads();
    mn = min(min(ired[0], ired[1]), min(ired[2], ired[3]));
    mx = max(max(ired[4], ired[5]), max(ired[6], ired[7]));
    __syncthreads();
}
__device__ __forceinline__ int block_isum(int v, int* ired) {
    for (int m = 32; m; m >>= 1) v += __shfl_xor(v, m);
    int w = threadIdx.x >> 6;
    if ((threadIdx.x & 63) == 0) ired[w] = v;
    __syncthreads();
    v = ired[0] + ired[1] + ired[2] + ired[3];
    __syncthreads();
    return v;
}

// =================== kA1: x min/max partials (pure streaming) ===================
__global__ __launch_bounds__(256) void kA1(const float4* __restrict__ x4,
                                           char* __restrict__ ws) {
    __shared__ float sred[8];
    float mn = 0.0f, mx = 0.0f;    // padding zeros included
    int base = blockIdx.x * blockDim.x + threadIdx.x;
    int stride = NT_ * 256;
    #pragma unroll
    for (int k = 0; k < 8; ++k) {
        float4 v = x4[base + k * stride];
        mn = fminf(mn, fminf(fminf(v.x, v.y), fminf(v.z, v.w)));
        mx = fmaxf(mx, fmaxf(fmaxf(v.x, v.y), fmaxf(v.z, v.w)));
    }
    block_fminmax(mn, mx, sred);
    if (threadIdx.x == 0) {
        ((float*)(ws + OFF_PBMIN))[blockIdx.x] = mn;
        ((float*)(ws + OFF_PBMAX))[blockIdx.x] = mx;
    }
}

// ========== kA2: reduce partials -> sx/zx; weight quant (sx-independent) ==========
__global__ __launch_bounds__(256) void kA2(const float* __restrict__ wgt,
                                           const int* __restrict__ abit_p,
                                           char* __restrict__ ws) {
    __shared__ float sred[8];
    __shared__ int ired[8];
    if (blockIdx.x == CO_) {
        const float* pbmin = (const float*)(ws + OFF_PBMIN);
        const float* pbmax = (const float*)(ws + OFF_PBMAX);
        float mn = 0.0f, mx = 0.0f;
        for (int i = threadIdx.x; i < NT_; i += 256) {
            mn = fminf(mn, pbmin[i]);
            mx = fmaxf(mx, pbmax[i]);
        }
        block_fminmax(mn, mx, sred);
        if (threadIdx.x == 0) {
            int abit = read_abit(abit_p);
            float nlv = (float)((1 << abit) - 1);
            float sx = nlv / fmaxf(mx - mn, 1e-8f);
            float zx = rintf(sx * mn) + (float)(1 << (abit - 1));
            ((float*)(ws + OFF_SXZX))[0] = sx;
            ((float*)(ws + OFF_SXZX))[1] = zx;
        }
        return;
    }
    int o = blockIdx.x;
    const float* wr = wgt + o * F_;
    float mn = 3.4e38f, mx = -3.4e38f;
    for (int f = threadIdx.x; f < F_; f += 256) {
        float v = wr[f];
        mn = fminf(mn, v); mx = fmaxf(mx, v);
    }
    block_fminmax(mn, mx, sred);
    float sw = 255.0f / fmaxf(mx - mn, 1e-8f);
    float zw = rintf(sw * mn) + 128.0f;
    signed char* qw = (signed char*)(ws + OFF_QW);
    int qsum = 0;
    for (int f = threadIdx.x; f < F_; f += 256) {
        float q = fminf(fmaxf(rintf(sw * wr[f] - zw), -128.0f), 127.0f);
        int qi = (int)q;
        qsum += qi;
        int c = f / 9, j = f - c * 9;
        qw[j * 16384 + (c >> 4) * 2048 + (o << 4) + (c & 15)] = (signed char)qi;
    }
    qsum = block_isum(qsum, ired);
    if (threadIdx.x == 0) {
        ((int*)(ws + OFF_QS))[o]  = qsum;
        ((int*)(ws + OFF_ZPW))[o] = (int)zw;
        ((float*)(ws + OFF_SW))[o] = sw;
    }
}

// ========= kP2x: quantize x to channel-last qx_t + per-pixel channel sums =========
__global__ __launch_bounds__(256) void kP2x(const float* __restrict__ x,
                                            const int* __restrict__ abit_p,
                                            char* __restrict__ ws) {
    __shared__ int ssum[4][64];
    float sx = ((const float*)(ws + OFF_SXZX))[0];
    float zx = ((const float*)(ws + OFF_SXZX))[1];
    int abit = read_abit(abit_p);
    int nx = 1 << (abit - 1);
    float lo = -(float)nx, hif = (float)(nx - 1);
    signed char* qxt = (signed char*)(ws + OFF_QX);
    int gid = swz_tile(blockIdx.x);
    int b = gid / 49, lcq = gid - b * 49;
    int l0 = lcq * 64;
    int t = threadIdx.x, lane = t & 63, cgp = t >> 6;
    int l = l0 + lane;
    const float* xb = x + ((size_t)b * C_) * L_ + l;
    int4* dst = (int4*)(qxt + ((size_t)(b * L_ + l)) * 128);
    int psum = 0;
    #pragma unroll
    for (int ii = 0; ii < 2; ++ii) {
        int c16 = (cgp + 4 * ii) * 16;
        int wds[4];
        #pragma unroll
        for (int k = 0; k < 4; ++k) {
            int wv = 0;
            #pragma unroll
            for (int e = 0; e < 4; ++e) {
                int c = c16 + 4 * k + e;
                float v = xb[(size_t)c * L_];
                int qi = (int)fminf(fmaxf(rintf(sx * v - zx), lo), hif);
                psum += qi;
                wv |= (qi & 255) << (8 * e);
            }
            wds[k] = wv;
        }
        int4 vv; vv.x = wds[0]; vv.y = wds[1]; vv.z = wds[2]; vv.w = wds[3];
        dst[c16 >> 4] = vv;
    }
    ssum[cgp][lane] = psum;
    __syncthreads();
    if (cgp == 0) {
        int* S = (int*)(ws + OFF_S);
        S[b * L_ + l] = ssum[0][lane] + ssum[1][lane] + ssum[2][lane] + ssum[3][lane];
    }
}

// ========= kGEMM: 64Mx128N MFMA int8 GEMM, res write + min/max partials =========
__global__ __launch_bounds__(256, 4) void kGEMM(const float* __restrict__ bias,
                                                const int* __restrict__ abit_p,
                                                char* __restrict__ ws) {
    __shared__ __align__(16) char pool[25760];
    __shared__ int ired[8];

    signed char* As = (signed char*)pool;
    signed char* Bs = (signed char*)(pool + 8192);
    int* S_s = (int*)(pool + 24576);
    int* sq  = (int*)(pool + 25504);
    const signed char* qxt = (const signed char*)(ws + OFF_QX);
    const signed char* qw  = (const signed char*)(ws + OFF_QW);
    const int* Sg  = (const int*)(ws + OFF_S);
    const int* zpw = (const int*)(ws + OFF_ZPW);

    float sx = ((const float*)(ws + OFF_SXZX))[0];
    float zx = ((const float*)(ws + OFF_SXZX))[1];
    int abit = read_abit(abit_p);

    int t = threadIdx.x;
    int mg = swz_tile(blockIdx.x) * 64;
    int b = mg / L_, l0 = mg - b * L_;
    int prow0 = l0 / HW_;
    int nx = 1 << (abit - 1);
    int q0 = min(max(-(int)zx, -nx), nx - 1);
    int pw = (q0 & 255) * 0x01010101;
    int4 pad4; pad4.x = pw; pad4.y = pw; pad4.z = pw; pad4.w = pw;
    int padS = C_ * q0;
    const signed char* qxtb = qxt + (size_t)b * L_ * 128;
    const int* Sb = Sg + b * L_;

    int chA = t & 7, rowA0 = t >> 3, rowA1 = rowA0 + 32;
    int li0 = l0 + rowA0, li1 = l0 + rowA1;
    int oh0 = li0 / HW_, ow0 = li0 - oh0 * HW_;
    int oh1 = li1 / HW_, ow1 = li1 - oh1 * HW_;

    int4 a0, a1, br0, br1, br2, br3;
    #define P3_LOAD_A(J) do {                                                          \
        int kh = (J) / 3 - 1, kw = (J) % 3 - 1;                                        \
        int ih = oh0 + kh, iw = ow0 + kw;                                              \
        a0 = ((unsigned)ih < HW_ && (unsigned)iw < HW_)                                \
             ? *(const int4*)(qxtb + ((ih * HW_ + iw) << 7) + (chA << 4)) : pad4;      \
        ih = oh1 + kh; iw = ow1 + kw;                                                  \
        a1 = ((unsigned)ih < HW_ && (unsigned)iw < HW_)                                \
             ? *(const int4*)(qxtb + ((ih * HW_ + iw) << 7) + (chA << 4)) : pad4;      \
    } while (0)
    #define P3_LOAD_B(J) do {                                                          \
        const int4* src = (const int4*)(qw + (J) * 16384);                             \
        br0 = src[t]; br1 = src[256 + t]; br2 = src[512 + t]; br3 = src[768 + t];      \
    } while (0)

    P3_LOAD_A(0); P3_LOAD_B(0);
    if (t < 232) {
        int ri = t / 58, c1 = t - ri * 58;
        int ih = prow0 - 1 + ri, iw = c1 - 1;
        S_s[t] = ((unsigned)ih < HW_ && (unsigned)iw < HW_) ? Sb[ih * HW_ + iw] : padS;
    }
    __syncthreads();
    if (t < 64) {
        int l = l0 + t;
        int oh = l / HW_, ow = l - oh * HW_;
        int ri = oh - prow0 + 1, ci = ow + 1;
        int s = 0;
        #pragma unroll
        for (int dr = -1; dr <= 1; ++dr)
            #pragma unroll
            for (int dc = -1; dc <= 1; ++dc)
                s += S_s[(ri + dr) * 58 + ci + dc];
        sq[t] = s;
    }

    int lane = t & 63, w = t >> 6;
    int wm = (w >> 1) << 5, wn = (w & 1) << 6;
    int r = lane & 31, hi = lane >> 5;
    i32x16 acc0, acc1;
    #pragma unroll
    for (int i = 0; i < 16; ++i) { acc0[i] = 0; acc1[i] = 0; }

    #pragma unroll
    for (int j = 0; j < 9; ++j) {
        if (j > 0) __syncthreads();            // WAR: previous tap's reads done
        *(int4*)&As[(rowA0 << 7) + ((chA ^ (rowA0 & 7)) << 4)] = a0;
        *(int4*)&As[(rowA1 << 7) + ((chA ^ (rowA1 & 7)) << 4)] = a1;
        {
            int4* d = (int4*)Bs;
            d[t] = br0; d[256 + t] = br1; d[512 + t] = br2; d[768 + t] = br3;
        }
        if (j < 8) { P3_LOAD_A(j + 1); P3_LOAD_B(j + 1); }
        __syncthreads();                        // RAW: tile visible
        i32x4 af[4], bf0[4], bf1[4];
        #pragma unroll
        for (int kk = 0; kk < 4; ++kk) {
            int ch2 = kk * 2 + hi, row = wm + r;
            af[kk]  = *(const i32x4*)&As[(row << 7) + ((ch2 ^ (row & 7)) << 4)];
            bf0[kk] = *(const i32x4*)&Bs[ch2 * 2048 + ((wn + r) << 4)];
            bf1[kk] = *(const i32x4*)&Bs[ch2 * 2048 + ((wn + 32 + r) << 4)];
        }
        #pragma unroll
        for (int kk = 0; kk < 4; ++kk) {
            acc0 = __builtin_amdgcn_mfma_i32_32x32x32_i8(af[kk], bf0[kk], acc0, 0, 0, 0);
            acc1 = __builtin_amdgcn_mfma_i32_32x32x32_i8(af[kk], bf1[kk], acc1, 0, 0, 0);
        }
    }
    #undef P3_LOAD_A
    #undef P3_LOAD_B

    int o0 = wn + r, o1 = wn + 32 + r;
    const int* qs = (const int*)(ws + OFF_QS);
    const float* swp = (const float*)(ws + OFF_SW);
    int zxi = (int)zx;
    int zw0 = zpw[o0], zw1 = zpw[o1];
    int c0 = zxi * qs[o0] + F_ * zw0 * zxi + (int)rintf(swp[o0] * sx * bias[o0]);
    int c1 = zxi * qs[o1] + F_ * zw1 * zxi + (int)rintf(swp[o1] * sx * bias[o1]);
    int lmin = INT32_MAX, lmax = INT32_MIN;
    int* resp = (int*)(ws + OFF_RES);
    #pragma unroll
    for (int g = 0; g < 16; ++g) {
        int row = wm + (g & 3) + ((g >> 2) << 3) + (hi << 2);
        int s = sq[row];
        int v0 = acc0[g] + zw0 * s + c0;
        int v1 = acc1[g] + zw1 * s + c1;
        lmin = min(lmin, min(v0, v1));
        lmax = max(lmax, max(v0, v1));
        int m = mg + row;
        resp[m * CO_ + o0] = v0;
        resp[m * CO_ + o1] = v1;
    }
    block_iminmax(lmin, lmax, ired);
    if (t == 0) {
        ((int*)(ws + OFF_PRMIN))[blockIdx.x] = lmin;
        ((int*)(ws + OFF_PRMAX))[blockIdx.x] = lmax;
    }
}

// ========= kDEQ: reduce r-partials + requant/dequant + transpose + store =========
__global__ __launch_bounds__(256) void kDEQ(const int* __restrict__ abit_p,
                                            char* __restrict__ ws,
                                            float* __restrict__ out) {
    __shared__ int tile[64 * 65];
    __shared__ int ired[8];
    float sxv = ((const float*)(ws + OFF_SXZX))[0];
    int abit = read_abit(abit_p);
    float nlv = (float)((1 << abit) - 1);

    const int* prmin = (const int*)(ws + OFF_PRMIN);
    const int* prmax = (const int*)(ws + OFF_PRMAX);
    int rmin = INT32_MAX, rmax = INT32_MIN;
    for (int i = threadIdx.x; i < NT_; i += 256) {
        rmin = min(rmin, prmin[i]);
        rmax = max(rmax, prmax[i]);
    }
    block_iminmax(rmin, rmax, ired);

    const int* res = (const int*)(ws + OFF_RES);
    const float* scale_w = (const float*)(ws + OFF_SW);
    int t = threadIdx.x;
    int bid = blockIdx.x;
    int lcq = bid % 49; int tmp2 = bid / 49; int ocq = tmp2 & 1; int b = tmp2 >> 1;
    int l0 = lcq * 64, o0 = ocq * 64;

    const int* resb = res + ((size_t)(b * L_ + l0)) * CO_ + o0;
    #pragma unroll
    for (int i = 0; i < 4; ++i) {
        int lr = (t >> 4) + i * 16;
        int oc4 = (t & 15) * 4;
        int4 v = *(const int4*)(resb + lr * CO_ + oc4);
        int* d = &tile[lr * 65 + oc4];
        d[0] = v.x; d[1] = v.y; d[2] = v.z; d[3] = v.w;
    }
    int nxq = 1 << (abit - 1);
    float sr = nlv / fmaxf((float)rmax - (float)rmin, 1e-8f);
    float zr = rintf(sr * (float)rmin) + (float)nxq;
    float lo = -(float)nxq, hiq = (float)(nxq - 1);
    __syncthreads();
    #pragma unroll
    for (int i = 0; i < 4; ++i) {
        int o = (t >> 4) + i * 16;
        int l4 = (t & 15) * 4;
        float swsx = scale_w[o0 + o] * sxv;
        float4 f;
        #pragma unroll
        for (int jj = 0; jj < 4; ++jj) {
            int rv = tile[(l4 + jj) * 65 + o];
            float q = fminf(fmaxf(rintf(sr * (float)rv - zr), lo), hiq);
            ((float*)&f)[jj] = ((q + zr) / sr) / swsx;
        }
        *(float4*)(out + ((size_t)(b * CO_ + o0 + o)) * L_ + l0 + l4) = f;
    }
}

// ---------------- launch ----------------

extern "C" void kernel_launch(void* const* d_in, const int* in_sizes, int n_in,
                              void* d_out, int out_size, void* d_ws, size_t ws_size,
                              hipStream_t stream) {
    const float* x      = (const float*)d_in[0];
    const float* weight = (const float*)d_in[1];
    const float* bias   = (const float*)d_in[2];
    const int*   abit   = (const int*)d_in[3];
    float* out = (float*)d_out;
    char* ws = (char*)d_ws;

    kA1<<<NT_, 256, 0, stream>>>((const float4*)x, ws);
    kA2<<<CO_ + 1, 256, 0, stream>>>(weight, abit, ws);
    kP2x<<<NT_, 256, 0, stream>>>(x, abit, ws);
    kGEMM<<<NT_, 256, 0, stream>>>(bias, abit, ws);
    kDEQ<<<1568, 256, 0, stream>>>(abit, ws, out);
}

// Round 16
// 53.882 us; speedup vs baseline: 1.7666x; 1.0214x over previous
//
#include <hip/hip_runtime.h>
#include <stdint.h>

#pragma clang fp contract(off)

typedef __attribute__((ext_vector_type(4))) int i32x4;
typedef __attribute__((ext_vector_type(16))) int i32x16;

#define B_    16
#define C_    128
#define HW_   56
#define L_    3136
#define CO_   128
#define F_    1152
#define M_    50176
#define NT_   784          // tiles (8 XCD * 98), 64 rows each

// ---- workspace layout (bytes) ----
#define OFF_PBMIN 0        // float[784]
#define OFF_PBMAX 4096     // float[784]
#define OFF_PRMIN 8192     // int[784]
#define OFF_PRMAX 12288    // int[784]
#define OFF_SW    16384    // float scale_w[128]
#define OFF_ZPW   16896    // int zp_w[128]
#define OFF_SXZX  17408    // float {sx, zx}
#define OFF_CNT   17536    // unsigned sync counters: 8 shards x 64B = 512
#define OFF_QS    18048    // int qsum[128]
#define OFF_QW    18560    // int8 qw2[j][ch][o][16] = 147456 -> ends 166016
#define OFF_QX    166016   // int8 qx_t[b][l][c] = 6422528 -> ends 6588544
#define OFF_S     6588544  // int S[b][3136] = 200704 -> ends 6789248
#define OFF_RES   6789248  // int res[50176][128] (FALLBACK PATH ONLY)

__device__ __forceinline__ int read_abit(const int* p) {
    int i = *p;
    if (i > 0 && i < 32) return i;
    float f = __int_as_float(i);
    int fi = (int)f;
    return (fi > 0 && fi < 32) ? fi : 8;
}

__device__ __forceinline__ int swz_tile(int blk) {
    return (blk & 7) * 98 + (blk >> 3);    // bijective on [0,784)
}

// ---- sharded grid barrier (relies on coop co-residency; counters pre-zeroed) ----
__device__ __forceinline__ void gsync(char* ws) {
    unsigned* base = (unsigned*)(ws + OFF_CNT);
    __syncthreads();
    if (threadIdx.x == 0) {
        __threadfence();                    // release
        atomicAdd(&base[(blockIdx.x & 7) * 16], 1u);
    }
    if (threadIdx.x < 8) {
        while (__hip_atomic_load(&base[threadIdx.x * 16],
                                 __ATOMIC_RELAXED, __HIP_MEMORY_SCOPE_AGENT) < 98u)
            __builtin_amdgcn_s_sleep(2);
    }
    __threadfence();                        // acquire
    __syncthreads();
}

// ---- block-wide reductions (256 threads) ----
__device__ __forceinline__ void block_fminmax(float& mn, float& mx, float* sred) {
    for (int m = 32; m; m >>= 1) {
        mn = fminf(mn, __shfl_xor(mn, m));
        mx = fmaxf(mx, __shfl_xor(mx, m));
    }
    int w = threadIdx.x >> 6;
    if ((threadIdx.x & 63) == 0) { sred[w] = mn; sred[4 + w] = mx; }
    __syncthreads();
    mn = fminf(fminf(sred[0], sred[1]), fminf(sred[2], sred[3]));
    mx = fmaxf(fmaxf(sred[4], sred[5]), fmaxf(sred[6], sred[7]));
    __syncthreads();
}
__device__ __forceinline__ void block_iminmax(int& mn, int& mx, int* ired) {
    for (int m = 32; m; m >>= 1) {
        mn = min(mn, __shfl_xor(mn, m));
        mx = max(mx, __shfl_xor(mx, m));
    }
    int w = threadIdx.x >> 6;
    if ((threadIdx.x & 63) == 0) { ired[w] = mn; ired[4 + w] = mx; }
    __syncthreads();
    mn = min(min(ired[0], ired[1]), min(ired[2], ired[3]));
    mx = max(max(ired[4], ired[5]), max(ired[6], ired[7]));
    __syncthreads();
}
__device__ __forceinline__ int block_isum(int v, int* ired) {
    for (int m = 32; m; m >>= 1) v += __shfl_xor(v, m);
    int w = threadIdx.x >> 6;
    if ((threadIdx.x & 63) == 0) ired[w] = v;
    __syncthreads();
    v = ired[0] + ired[1] + ired[2] + ired[3];
    __syncthreads();
    return v;
}

// ====== kA: blocks 0..783 x-minmax partials; 784..911 weight quant ======
__global__ __launch_bounds__(256) void kA(const float4* __restrict__ x4,
                                          const float* __restrict__ wgt,
                                          char* __restrict__ ws) {
    __shared__ float sred[8];
    __shared__ int ired[8];
    int blk = blockIdx.x;
    if (blk < NT_) {
        float mn = 0.0f, mx = 0.0f;    // padding zeros included
        int base = blk * blockDim.x + threadIdx.x;
        int stride = NT_ * 256;
        #pragma unroll
        for (int k = 0; k < 8; ++k) {
            float4 v = x4[base + k * stride];
            mn = fminf(mn, fminf(fminf(v.x, v.y), fminf(v.z, v.w)));
            mx = fmaxf(mx, fmaxf(fmaxf(v.x, v.y), fmaxf(v.z, v.w)));
        }
        block_fminmax(mn, mx, sred);
        if (threadIdx.x == 0) {
            ((float*)(ws + OFF_PBMIN))[blk] = mn;
            ((float*)(ws + OFF_PBMAX))[blk] = mx;
        }
        return;
    }
    // weight quant (sx-independent): qw2[j][ch][o][16] pack + qsum/zpw/sw
    int o = blk - NT_;
    const float* wr = wgt + o * F_;
    float mn = 3.4e38f, mx = -3.4e38f;
    for (int f = threadIdx.x; f < F_; f += 256) {
        float v = wr[f];
        mn = fminf(mn, v); mx = fmaxf(mx, v);
    }
    block_fminmax(mn, mx, sred);
    float sw = 255.0f / fmaxf(mx - mn, 1e-8f);
    float zw = rintf(sw * mn) + 128.0f;
    signed char* qw = (signed char*)(ws + OFF_QW);
    int qsum = 0;
    for (int f = threadIdx.x; f < F_; f += 256) {
        float q = fminf(fmaxf(rintf(sw * wr[f] - zw), -128.0f), 127.0f);
        int qi = (int)q;
        qsum += qi;
        int c = f / 9, j = f - c * 9;
        qw[j * 16384 + (c >> 4) * 2048 + (o << 4) + (c & 15)] = (signed char)qi;
    }
    qsum = block_isum(qsum, ired);
    if (threadIdx.x == 0) {
        ((int*)(ws + OFF_QS))[o]  = qsum;
        ((int*)(ws + OFF_ZPW))[o] = (int)zw;
        ((float*)(ws + OFF_SW))[o] = sw;
    }
}

// ====== kP2x: per-block sx reduce + quantize x to qx_t + channel sums S ======
__global__ __launch_bounds__(256) void kP2x(const float* __restrict__ x,
                                            const int* __restrict__ abit_p,
                                            char* __restrict__ ws) {
    __shared__ float sred[8];
    __shared__ int ssum[4][64];
    // redundant per-block reduce of partials (6 KB, L2-hit) -> identical sx/zx
    float mn = 0.0f, mx = 0.0f;
    {
        const float* pbmin = (const float*)(ws + OFF_PBMIN);
        const float* pbmax = (const float*)(ws + OFF_PBMAX);
        for (int i = threadIdx.x; i < NT_; i += 256) {
            mn = fminf(mn, pbmin[i]);
            mx = fmaxf(mx, pbmax[i]);
        }
        block_fminmax(mn, mx, sred);
    }
    int abit = read_abit(abit_p);
    float nlv = (float)((1 << abit) - 1);
    float sx = nlv / fmaxf(mx - mn, 1e-8f);
    float zx = rintf(sx * mn) + (float)(1 << (abit - 1));
    if (threadIdx.x == 0 && blockIdx.x == 0) {
        ((float*)(ws + OFF_SXZX))[0] = sx;
        ((float*)(ws + OFF_SXZX))[1] = zx;
    }
    int nx = 1 << (abit - 1);
    float lo = -(float)nx, hif = (float)(nx - 1);
    signed char* qxt = (signed char*)(ws + OFF_QX);
    int gid = swz_tile(blockIdx.x);
    int b = gid / 49, lcq = gid - b * 49;
    int l0 = lcq * 64;
    int t = threadIdx.x, lane = t & 63, cgp = t >> 6;
    int l = l0 + lane;
    const float* xb = x + ((size_t)b * C_) * L_ + l;
    int4* dst = (int4*)(qxt + ((size_t)(b * L_ + l)) * 128);
    int psum = 0;
    #pragma unroll
    for (int ii = 0; ii < 2; ++ii) {
        int c16 = (cgp + 4 * ii) * 16;
        int wds[4];
        #pragma unroll
        for (int k = 0; k < 4; ++k) {
            int wv = 0;
            #pragma unroll
            for (int e = 0; e < 4; ++e) {
                int c = c16 + 4 * k + e;
                float v = xb[(size_t)c * L_];
                int qi = (int)fminf(fmaxf(rintf(sx * v - zx), lo), hif);
                psum += qi;
                wv |= (qi & 255) << (8 * e);
            }
            wds[k] = wv;
        }
        int4 vv; vv.x = wds[0]; vv.y = wds[1]; vv.z = wds[2]; vv.w = wds[3];
        dst[c16 >> 4] = vv;
    }
    ssum[cgp][lane] = psum;
    __syncthreads();
    if (cgp == 0) {
        int* S = (int*)(ws + OFF_S);
        S[b * L_ + l] = ssum[0][lane] + ssum[1][lane] + ssum[2][lane] + ssum[3][lane];
    }
}

// ---- P3: 64Mx128N MFMA int8 GEMM tile; corrected accs stay in registers ----
// pool layout: As 0..8191 | Bs 8192..24575 | S_s 24576..25503 | sq 25504..25759
template <bool WRITE_RES>
__device__ __forceinline__ void dev_p3(char* __restrict__ ws, char* pool, int* ired,
                                       const float* __restrict__ bias,
                                       int abit, float sx, float zx,
                                       i32x16& acc0, i32x16& acc1) {
    signed char* As = (signed char*)pool;
    signed char* Bs = (signed char*)(pool + 8192);
    int* S_s = (int*)(pool + 24576);
    int* sq  = (int*)(pool + 25504);
    const signed char* qxt = (const signed char*)(ws + OFF_QX);
    const signed char* qw  = (const signed char*)(ws + OFF_QW);
    const int* Sg  = (const int*)(ws + OFF_S);
    const int* zpw = (const int*)(ws + OFF_ZPW);

    int t = threadIdx.x;
    int mg = swz_tile(blockIdx.x) * 64;
    int b = mg / L_, l0 = mg - b * L_;
    int prow0 = l0 / HW_;
    int nx = 1 << (abit - 1);
    int q0 = min(max(-(int)zx, -nx), nx - 1);
    int pw = (q0 & 255) * 0x01010101;
    int4 pad4; pad4.x = pw; pad4.y = pw; pad4.z = pw; pad4.w = pw;
    int padS = C_ * q0;
    const signed char* qxtb = qxt + (size_t)b * L_ * 128;
    const int* Sb = Sg + b * L_;

    int chA = t & 7, rowA0 = t >> 3, rowA1 = rowA0 + 32;
    int li0 = l0 + rowA0, li1 = l0 + rowA1;
    int oh0 = li0 / HW_, ow0 = li0 - oh0 * HW_;
    int oh1 = li1 / HW_, ow1 = li1 - oh1 * HW_;

    int4 a0, a1, br0, br1, br2, br3;
    #define P3_LOAD_A(J) do {                                                          \
        int kh = (J) / 3 - 1, kw = (J) % 3 - 1;                                        \
        int ih = oh0 + kh, iw = ow0 + kw;                                              \
        a0 = ((unsigned)ih < HW_ && (unsigned)iw < HW_)                                \
             ? *(const int4*)(qxtb + ((ih * HW_ + iw) << 7) + (chA << 4)) : pad4;      \
        ih = oh1 + kh; iw = ow1 + kw;                                                  \
        a1 = ((unsigned)ih < HW_ && (unsigned)iw < HW_)                                \
             ? *(const int4*)(qxtb + ((ih * HW_ + iw) << 7) + (chA << 4)) : pad4;      \
    } while (0)
    #define P3_LOAD_B(J) do {                                                          \
        const int4* src = (const int4*)(qw + (J) * 16384);                             \
        br0 = src[t]; br1 = src[256 + t]; br2 = src[512 + t]; br3 = src[768 + t];      \
    } while (0)

    P3_LOAD_A(0); P3_LOAD_B(0);
    if (t < 232) {
        int ri = t / 58, c1 = t - ri * 58;
        int ih = prow0 - 1 + ri, iw = c1 - 1;
        S_s[t] = ((unsigned)ih < HW_ && (unsigned)iw < HW_) ? Sb[ih * HW_ + iw] : padS;
    }
    __syncthreads();
    if (t < 64) {
        int l = l0 + t;
        int oh = l / HW_, ow = l - oh * HW_;
        int ri = oh - prow0 + 1, ci = ow + 1;
        int s = 0;
        #pragma unroll
        for (int dr = -1; dr <= 1; ++dr)
            #pragma unroll
            for (int dc = -1; dc <= 1; ++dc)
                s += S_s[(ri + dr) * 58 + ci + dc];
        sq[t] = s;
    }

    int lane = t & 63, w = t >> 6;
    int wm = (w >> 1) << 5, wn = (w & 1) << 6;
    int r = lane & 31, hi = lane >> 5;
    #pragma unroll
    for (int i = 0; i < 16; ++i) { acc0[i] = 0; acc1[i] = 0; }

    #pragma unroll
    for (int j = 0; j < 9; ++j) {
        if (j > 0) __syncthreads();            // WAR
        *(int4*)&As[(rowA0 << 7) + ((chA ^ (rowA0 & 7)) << 4)] = a0;
        *(int4*)&As[(rowA1 << 7) + ((chA ^ (rowA1 & 7)) << 4)] = a1;
        {
            int4* d = (int4*)Bs;
            d[t] = br0; d[256 + t] = br1; d[512 + t] = br2; d[768 + t] = br3;
        }
        if (j < 8) { P3_LOAD_A(j + 1); P3_LOAD_B(j + 1); }
        __syncthreads();                        // RAW
        i32x4 af[4], bf0[4], bf1[4];
        #pragma unroll
        for (int kk = 0; kk < 4; ++kk) {
            int ch2 = kk * 2 + hi, row = wm + r;
            af[kk]  = *(const i32x4*)&As[(row << 7) + ((ch2 ^ (row & 7)) << 4)];
            bf0[kk] = *(const i32x4*)&Bs[ch2 * 2048 + ((wn + r) << 4)];
            bf1[kk] = *(const i32x4*)&Bs[ch2 * 2048 + ((wn + 32 + r) << 4)];
        }
        #pragma unroll
        for (int kk = 0; kk < 4; ++kk) {
            acc0 = __builtin_amdgcn_mfma_i32_32x32x32_i8(af[kk], bf0[kk], acc0, 0, 0, 0);
            acc1 = __builtin_amdgcn_mfma_i32_32x32x32_i8(af[kk], bf1[kk], acc1, 0, 0, 0);
        }
    }
    #undef P3_LOAD_A
    #undef P3_LOAD_B

    int o0 = wn + r, o1 = wn + 32 + r;
    const int* qs = (const int*)(ws + OFF_QS);
    const float* swp = (const float*)(ws + OFF_SW);
    int zxi = (int)zx;
    int zw0 = zpw[o0], zw1 = zpw[o1];
    int c0 = zxi * qs[o0] + F_ * zw0 * zxi + (int)rintf(swp[o0] * sx * bias[o0]);
    int c1 = zxi * qs[o1] + F_ * zw1 * zxi + (int)rintf(swp[o1] * sx * bias[o1]);
    int lmin = INT32_MAX, lmax = INT32_MIN;
    int* resp = (int*)(ws + OFF_RES);
    #pragma unroll
    for (int g = 0; g < 16; ++g) {
        int row = wm + (g & 3) + ((g >> 2) << 3) + (hi << 2);
        int s = sq[row];
        int v0 = acc0[g] + zw0 * s + c0;
        int v1 = acc1[g] + zw1 * s + c1;
        acc0[g] = v0; acc1[g] = v1;
        lmin = min(lmin, min(v0, v1));
        lmax = max(lmax, max(v0, v1));
        if (WRITE_RES) {
            int m = mg + row;
            resp[m * CO_ + o0] = v0;
            resp[m * CO_ + o1] = v1;
        }
    }
    block_iminmax(lmin, lmax, ired);
    if (t == 0) {
        ((int*)(ws + OFF_PRMIN))[blockIdx.x] = lmin;
        ((int*)(ws + OFF_PRMAX))[blockIdx.x] = lmax;
    }
    __syncthreads();
}

__device__ __forceinline__ void dev_reduce_pr(const char* ws, int* ired,
                                              int& rmin, int& rmax) {
    const int* prmin = (const int*)(ws + OFF_PRMIN);
    const int* prmax = (const int*)(ws + OFF_PRMAX);
    int mn = INT32_MAX, mx = INT32_MIN;
    for (int i = threadIdx.x; i < NT_; i += 256) {
        mn = min(mn, prmin[i]);
        mx = max(mx, prmax[i]);
    }
    block_iminmax(mn, mx, ired);
    rmin = mn; rmax = mx;
}

// ========== kCoop: GEMM (accs in regs) -> gsync -> reduce -> P4 store ==========
__global__ __launch_bounds__(256, 4) void kCoop(const float* __restrict__ bias,
                                                const int* __restrict__ abit_p,
                                                char* __restrict__ ws,
                                                float* __restrict__ out) {
    __shared__ __align__(16) char pool[33280];
    __shared__ int ired[8];

    float sx = ((const float*)(ws + OFF_SXZX))[0];
    float zx = ((const float*)(ws + OFF_SXZX))[1];
    int abit = read_abit(abit_p);

    i32x16 acc0, acc1;
    dev_p3<false>(ws, pool, ired, bias, abit, sx, zx, acc0, acc1);
    gsync(ws);

    int rmin, rmax;
    dev_reduce_pr(ws, ired, rmin, rmax);

    // P4: requant + dequant from registers; transpose via LDS; store out
    const float* swp = (const float*)(ws + OFF_SW);
    int t = threadIdx.x;
    int mg = swz_tile(blockIdx.x) * 64;
    int b = mg / L_, l0 = mg - b * L_;
    int lane = t & 63, w = t >> 6;
    int wm = (w >> 1) << 5, wn = (w & 1) << 6;
    int r = lane & 31, hi = lane >> 5;
    int o0 = wn + r, o1 = wn + 32 + r;
    int nx = 1 << (abit - 1);
    float nlev = (float)((1 << abit) - 1);
    float sr = nlev / fmaxf((float)rmax - (float)rmin, 1e-8f);
    float zr = rintf(sr * (float)rmin) + (float)nx;
    float lo = -(float)nx, hiq = (float)(nx - 1);
    float swsx0 = swp[o0] * sx, swsx1 = swp[o1] * sx;
    float* tile = (float*)pool;        // [64][129] f32 = 33024 B
    #pragma unroll
    for (int g = 0; g < 16; ++g) {
        int row = wm + (g & 3) + ((g >> 2) << 3) + (hi << 2);
        float qa = fminf(fmaxf(rintf(sr * (float)acc0[g] - zr), lo), hiq);
        float qb = fminf(fmaxf(rintf(sr * (float)acc1[g] - zr), lo), hiq);
        tile[row * 129 + o0] = ((qa + zr) / sr) / swsx0;
        tile[row * 129 + o1] = ((qb + zr) / sr) / swsx1;
    }
    __syncthreads();
    #pragma unroll
    for (int i = 0; i < 8; ++i) {
        int o = (t >> 4) + i * 16;
        int l4 = (t & 15) * 4;
        float4 f;
        #pragma unroll
        for (int jj = 0; jj < 4; ++jj)
            ((float*)&f)[jj] = tile[(l4 + jj) * 129 + o];
        *(float4*)(out + ((size_t)(b * CO_ + o)) * L_ + l0 + l4) = f;
    }
}

// =================== fallback (non-cooperative) path ===================
__global__ __launch_bounds__(256, 4) void fbGEMM(const float* __restrict__ bias,
                                                 const int* __restrict__ abit_p,
                                                 char* __restrict__ ws) {
    __shared__ __align__(16) char pool[25760];
    __shared__ int ired[8];
    float sx = ((const float*)(ws + OFF_SXZX))[0];
    float zx = ((const float*)(ws + OFF_SXZX))[1];
    int abit = read_abit(abit_p);
    i32x16 acc0, acc1;
    dev_p3<true>(ws, pool, ired, bias, abit, sx, zx, acc0, acc1);
}

__global__ __launch_bounds__(256) void fbDEQ(const int* __restrict__ abit_p,
                                             char* __restrict__ ws,
                                             float* __restrict__ out) {
    __shared__ int tile[64 * 65];
    __shared__ int ired[8];
    float sxv = ((const float*)(ws + OFF_SXZX))[0];
    int abit = read_abit(abit_p);
    float nlv = (float)((1 << abit) - 1);
    int rmin, rmax;
    dev_reduce_pr(ws, ired, rmin, rmax);

    const int* res = (const int*)(ws + OFF_RES);
    const float* scale_w = (const float*)(ws + OFF_SW);
    int t = threadIdx.x;
    int bid = blockIdx.x;
    int lcq = bid % 49; int tmp2 = bid / 49; int ocq = tmp2 & 1; int b = tmp2 >> 1;
    int l0 = lcq * 64, o0 = ocq * 64;

    const int* resb = res + ((size_t)(b * L_ + l0)) * CO_ + o0;
    #pragma unroll
    for (int i = 0; i < 4; ++i) {
        int lr = (t >> 4) + i * 16;
        int oc4 = (t & 15) * 4;
        int4 v = *(const int4*)(resb + lr * CO_ + oc4);
        int* d = &tile[lr * 65 + oc4];
        d[0] = v.x; d[1] = v.y; d[2] = v.z; d[3] = v.w;
    }
    int nxq = 1 << (abit - 1);
    float sr = nlv / fmaxf((float)rmax - (float)rmin, 1e-8f);
    float zr = rintf(sr * (float)rmin) + (float)nxq;
    float lo = -(float)nxq, hiq = (float)(nxq - 1);
    __syncthreads();
    #pragma unroll
    for (int i = 0; i < 4; ++i) {
        int o = (t >> 4) + i * 16;
        int l4 = (t & 15) * 4;
        float swsx = scale_w[o0 + o] * sxv;
        float4 f;
        #pragma unroll
        for (int jj = 0; jj < 4; ++jj) {
            int rv = tile[(l4 + jj) * 65 + o];
            float q = fminf(fmaxf(rintf(sr * (float)rv - zr), lo), hiq);
            ((float*)&f)[jj] = ((q + zr) / sr) / swsx;
        }
        *(float4*)(out + ((size_t)(b * CO_ + o0 + o)) * L_ + l0 + l4) = f;
    }
}

// ---------------- launch ----------------

extern "C" void kernel_launch(void* const* d_in, const int* in_sizes, int n_in,
                              void* d_out, int out_size, void* d_ws, size_t ws_size,
                              hipStream_t stream) {
    const float* x      = (const float*)d_in[0];
    const float* weight = (const float*)d_in[1];
    const float* bias   = (const float*)d_in[2];
    const int*   abit   = (const int*)d_in[3];
    float* out = (float*)d_out;
    char* ws = (char*)d_ws;

    int dev = 0;
    hipGetDevice(&dev);
    int ncu = 0;
    hipDeviceGetAttribute(&ncu, hipDeviceAttributeMultiprocessorCount, dev);
    int nb = 0;
    hipOccupancyMaxActiveBlocksPerMultiprocessor(&nb, (const void*)kCoop, 256, 0);

    kA<<<NT_ + CO_, 256, 0, stream>>>((const float4*)x, weight, ws);
    kP2x<<<NT_, 256, 0, stream>>>(x, abit, ws);

    if (nb > 0 && (long)nb * (long)ncu >= NT_) {
        hipMemsetAsync(ws + OFF_CNT, 0, 512, stream);
        kCoop<<<NT_, 256, 0, stream>>>(bias, abit, ws, out);
    } else {
        fbGEMM<<<NT_, 256, 0, stream>>>(bias, abit, ws);
        fbDEQ<<<1568, 256, 0, stream>>>(abit, ws, out);
    }
}